// Round 9
// baseline (449.089 us; speedup 1.0000x reference)
//
#include <hip/hip_runtime.h>

// Persistent fused 2-layer LSTM + FC + softmax for MI355X (gfx950).
// B=2048, T=256, H=64, IN=42. 512 blocks x 512 threads; block owns 4 rows.
// Waves 0-3: layer0(step i); waves 4-7: layer1(step i-1) (R7 pipeline);
// ping-pong LDS slots, 1 barrier/iter (R8).
//
// R9 changes:
// 1) 512 blocks x 4 rows -> 2 independent blocks per CU = 4 waves/SIMD.
//    Blocks don't share barriers, so one block's barrier drain is hidden
//    by the other block's compute (R8 was 41% idle at 2 waves/SIMD).
// 2) Row map m = 5r: the real cell index i equals quad for every lane ->
//    exactly 1 cell per lane (R8: 2), halving activation issue per wave.
// 3) A-fragments processed in q-halves (8 live regs) + launch_bounds(512,4)
//    to fit the 128-reg budget for 4 waves/SIMD.
// Arithmetic bitwise-identical to R8 (same MFMA/k-order/f16 rounding).

typedef _Float16 f16;
typedef _Float16 f16x2 __attribute__((ext_vector_type(2)));
typedef _Float16 f16x8 __attribute__((ext_vector_type(8)));
typedef float f32x4 __attribute__((ext_vector_type(4)));

namespace {
constexpr int kT = 256;
constexpr int kIn = 42;
constexpr int kH = 64;
constexpr int kRows = 4;          // batch rows per block
constexpr int kThr = 512;
constexpr int kKP = 136;          // LDS row stride in f16 (272 B)
constexpr int kSlot = 16 * kKP;   // one ping-pong slot (f16 elems)
}

__device__ __forceinline__ float sig_(float v) {
  return __fdividef(1.0f, 1.0f + __expf(-v));
}
__device__ __forceinline__ float tnh_(float v) {
  return __fdividef(2.0f, 1.0f + __expf(-2.0f * v)) - 1.0f;
}

__global__ __launch_bounds__(kThr, 4)
void lstm_occ_kernel(const float* __restrict__ x,
                     const float* __restrict__ Wih0, const float* __restrict__ Whh0,
                     const float* __restrict__ bih0, const float* __restrict__ bhh0,
                     const float* __restrict__ Wih1, const float* __restrict__ Whh1,
                     const float* __restrict__ bih1, const float* __restrict__ bhh1,
                     const float* __restrict__ Wfc, const float* __restrict__ bfc,
                     float* __restrict__ out) {
  // xh0 row m: [ x(t) (42) | h0 (64) | pad ]   (group A reads)
  // xh1 row m: [ h0 (64) | h1 (64) | pad ]     (group B reads)
  __shared__ __align__(16) f16 xh0[2 * kSlot];
  __shared__ __align__(16) f16 xh1[2 * kSlot];
  __shared__ float lg[kRows * 8];

  const int tid = threadIdx.x;
  const int w8 = tid >> 6;
  const bool isA = (w8 < 4);     // A: layer 0; B: layer 1
  const int w = w8 & 3;          // h-slice [16w, 16w+16)
  const int l = tid & 63;
  const int c = l & 15;
  const int quad = l >> 4;
  const int row0 = blockIdx.x * kRows;

  for (int i = tid; i < 2 * kSlot; i += kThr) { xh0[i] = (f16)0; xh1[i] = (f16)0; }

  // ---- one-time: this group's weights as MFMA B-fragments + biases ----
  f16x8 Bw[4][4];
  float bias[4];
#pragma unroll
  for (int a = 0; a < 4; ++a) {
    const int g = (w + 4 * a) * 16 + c;
    bias[a] = isA ? (bih0[g] + bhh0[g]) : (bih1[g] + bhh1[g]);
#pragma unroll
    for (int q = 0; q < 4; ++q) {
      f16x8 v;
#pragma unroll
      for (int j = 0; j < 8; ++j) {
        const int k = q * 32 + quad * 8 + j;
        float wv;
        if (isA)
          wv = (k < 42) ? Wih0[g * kIn + k] : (k < 106) ? Whh0[g * kH + (k - 42)] : 0.f;
        else
          wv = (k < 64) ? Wih1[g * kH + k] : Whh1[g * kH + (k - 64)];
        v[j] = (f16)wv;
      }
      Bw[a][q] = v;
    }
  }

  // Row map: batch row r -> M-row m = 5r (r in [0,4)). Real cell for lane
  // (quad,c): acc index i == quad, batch row r == quad, h == 16w + c.
  float cst = 0.f;               // single cell state per lane
  const int hcol = w * 16 + c;
  const int myq = quad;          // acc element that is real for this lane
  const int mym = 5 * quad;      // its M-row

  // x staging: 84 group-B threads, one float2 each; batch row srr -> m=5*srr
  const float* xbase = x + (size_t)row0 * kT * kIn;
  const int stid = tid - 256;
  const bool stager = (!isA) && (stid < 84);
  const int srr = stager ? stid / 21 : 0;
  const int sp = stager ? stid - srr * 21 : 0;
  const int sm = 5 * srr;

  if (stager) {  // pre-stage x(0) into slot 0
    const float2 v = *(const float2*)(xbase + (size_t)srr * kT * kIn + 2 * sp);
    f16x2 hv; hv.x = (f16)v.x; hv.y = (f16)v.y;
    *(f16x2*)&xh0[sm * kKP + 2 * sp] = hv;
  }
  __syncthreads();

  // iter i: A computes layer0(t=i), B computes layer1(t=i-1)
  for (int i = 0; i <= kT; ++i) {
    const int cur = i & 1, nxt = cur ^ 1;
    const bool act = isA ? (i < kT) : (i > 0);

    float2 xv;
    const bool havex = stager && (i + 1 < kT);
    if (havex)
      xv = *(const float2*)(xbase + (size_t)srr * kT * kIn + (size_t)(i + 1) * kIn + 2 * sp);

    if (act) {
      const f16* ar = (isA ? xh0 : xh1) + cur * kSlot + c * kKP + quad * 8;
      f32x4 acc[4];
#pragma unroll
      for (int a = 0; a < 4; ++a) acc[a] = (f32x4){bias[a], bias[a], bias[a], bias[a]};
      // q-halves: only 2 A-fragments (8 regs) live at a time
#pragma unroll
      for (int qh = 0; qh < 2; ++qh) {
        f16x8 A0 = __builtin_bit_cast(f16x8, *(const float4*)(ar + (2 * qh) * 32));
        f16x8 A1 = __builtin_bit_cast(f16x8, *(const float4*)(ar + (2 * qh + 1) * 32));
#pragma unroll
        for (int a = 0; a < 4; ++a)
          acc[a] = __builtin_amdgcn_mfma_f32_16x16x32_f16(A0, Bw[a][2 * qh], acc[a], 0, 0, 0);
#pragma unroll
        for (int a = 0; a < 4; ++a)
          acc[a] = __builtin_amdgcn_mfma_f32_16x16x32_f16(A1, Bw[a][2 * qh + 1], acc[a], 0, 0, 0);
      }
      // single real cell: acc element myq (== quad)
      const float gi = acc[0][myq], gf = acc[1][myq], gg = acc[2][myq], go = acc[3][myq];
      cst = sig_(gf) * cst + sig_(gi) * tnh_(gg);
      const f16 h = (f16)(sig_(go) * tnh_(cst));
      if (isA) {
        xh0[nxt * kSlot + mym * kKP + 42 + hcol] = h;  // A's next step
        xh1[nxt * kSlot + mym * kKP + hcol] = h;       // B's next iteration
      } else {
        xh1[nxt * kSlot + mym * kKP + 64 + hcol] = h;  // h1 recurrent input
      }
    }
    if (havex) {
      f16x2 hv; hv.x = (f16)xv.x; hv.y = (f16)xv.y;
      *(f16x2*)&xh0[nxt * kSlot + sm * kKP + 2 * sp] = hv;
    }
    __syncthreads();  // publish nxt-slot writes; next iter reads them as cur
  }

  // ---- FC + softmax. Final h1(T-1) is in slot 1 (kT even). ----
  if (tid < kRows * 5) {
    const int rr = tid / 5, oo = tid - rr * 5;
    const int m = 5 * rr;
    float a = bfc[oo];
#pragma unroll
    for (int j = 0; j < kH; ++j)
      a += (float)xh1[kSlot + m * kKP + 64 + j] * Wfc[oo * kH + j];
    lg[rr * 8 + oo] = a;
  }
  __syncthreads();
  if (tid < kRows) {
    const float v0 = lg[tid * 8 + 0], v1 = lg[tid * 8 + 1], v2 = lg[tid * 8 + 2],
                v3 = lg[tid * 8 + 3], v4 = lg[tid * 8 + 4];
    const float m = fmaxf(fmaxf(fmaxf(v0, v1), fmaxf(v2, v3)), v4);
    const float e0 = __expf(v0 - m), e1 = __expf(v1 - m), e2 = __expf(v2 - m),
                e3 = __expf(v3 - m), e4 = __expf(v4 - m);
    const float inv = __fdividef(1.0f, e0 + e1 + e2 + e3 + e4);
    float* o = out + (size_t)(row0 + tid) * 5;
    o[0] = e0 * inv; o[1] = e1 * inv; o[2] = e2 * inv; o[3] = e3 * inv; o[4] = e4 * inv;
  }
}

extern "C" void kernel_launch(void* const* d_in, const int* in_sizes, int n_in,
                              void* d_out, int out_size, void* d_ws, size_t ws_size,
                              hipStream_t stream) {
  (void)in_sizes; (void)n_in; (void)d_ws; (void)ws_size; (void)out_size;
  lstm_occ_kernel<<<dim3(512), dim3(kThr), 0, stream>>>(
      (const float*)d_in[0],
      (const float*)d_in[1], (const float*)d_in[2],
      (const float*)d_in[3], (const float*)d_in[4],
      (const float*)d_in[5], (const float*)d_in[6],
      (const float*)d_in[7], (const float*)d_in[8],
      (const float*)d_in[9], (const float*)d_in[10],
      (float*)d_out);
}

// Round 10
// 418.831 us; speedup vs baseline: 1.0722x; 1.0722x over previous
//
#include <hip/hip_runtime.h>

// Persistent fused 2-layer LSTM + FC + softmax for MI355X (gfx950).
// B=2048, T=256, H=64, IN=42. 512 blocks x 512 threads; block owns 4 rows.
// Waves 0-3: layer0(step i); waves 4-7: layer1(step i-1); ping-pong LDS,
// 1 barrier/iter. 2 independent blocks per CU = 4 waves/SIMD fill each
// other's barrier drains (R9 concept).
//
// R10 fixes vs R9 (which regressed on spill + dynamic indexing):
// 1) Row map m = 4r: real cell of lane (quad,c) is M-row 4*quad -> acc
//    element [0] for EVERY lane — static index, no cndmask extraction.
// 2) Register diet: q-halved A-fragments (8 live regs), static indices,
//    to fit the 128-reg/wave budget of 4 waves/SIMD without spilling.
//    Tripwire: WRITE_SIZE must stay ~40 KB.
// Arithmetic bitwise-identical to R8/R9 (same MFMA, k-order, f16 rounding).

typedef _Float16 f16;
typedef _Float16 f16x2 __attribute__((ext_vector_type(2)));
typedef _Float16 f16x8 __attribute__((ext_vector_type(8)));
typedef float f32x4 __attribute__((ext_vector_type(4)));

namespace {
constexpr int kT = 256;
constexpr int kIn = 42;
constexpr int kH = 64;
constexpr int kRows = 4;          // batch rows per block
constexpr int kThr = 512;
constexpr int kKP = 136;          // LDS row stride in f16 (272 B)
constexpr int kSlot = 16 * kKP;   // one ping-pong slot (f16 elems)
}

__device__ __forceinline__ float sig_(float v) {
  return __fdividef(1.0f, 1.0f + __expf(-v));
}
__device__ __forceinline__ float tnh_(float v) {
  return __fdividef(2.0f, 1.0f + __expf(-2.0f * v)) - 1.0f;
}

__global__ __launch_bounds__(kThr, 4)
void lstm_occ2_kernel(const float* __restrict__ x,
                      const float* __restrict__ Wih0, const float* __restrict__ Whh0,
                      const float* __restrict__ bih0, const float* __restrict__ bhh0,
                      const float* __restrict__ Wih1, const float* __restrict__ Whh1,
                      const float* __restrict__ bih1, const float* __restrict__ bhh1,
                      const float* __restrict__ Wfc, const float* __restrict__ bfc,
                      float* __restrict__ out) {
  // xh0 row m: [ x(t) (42) | h0 (64) | pad ]   (group A reads)
  // xh1 row m: [ h0 (64) | h1 (64) | pad ]     (group B reads)
  __shared__ __align__(16) f16 xh0[2 * kSlot];
  __shared__ __align__(16) f16 xh1[2 * kSlot];
  __shared__ float lg[kRows * 8];

  const int tid = threadIdx.x;
  const int w8 = tid >> 6;
  const bool isA = (w8 < 4);     // A: layer 0; B: layer 1
  const int w = w8 & 3;          // h-slice [16w, 16w+16)
  const int l = tid & 63;
  const int c = l & 15;
  const int quad = l >> 4;
  const int row0 = blockIdx.x * kRows;

  for (int i = tid; i < 2 * kSlot; i += kThr) { xh0[i] = (f16)0; xh1[i] = (f16)0; }

  // ---- one-time: this group's weights as MFMA B-fragments + biases ----
  f16x8 Bw[4][4];
  float bias[4];
#pragma unroll
  for (int a = 0; a < 4; ++a) {
    const int g = (w + 4 * a) * 16 + c;
    bias[a] = isA ? (bih0[g] + bhh0[g]) : (bih1[g] + bhh1[g]);
#pragma unroll
    for (int q = 0; q < 4; ++q) {
      f16x8 v;
#pragma unroll
      for (int j = 0; j < 8; ++j) {
        const int k = q * 32 + quad * 8 + j;
        float wv;
        if (isA)
          wv = (k < 42) ? Wih0[g * kIn + k] : (k < 106) ? Whh0[g * kH + (k - 42)] : 0.f;
        else
          wv = (k < 64) ? Wih1[g * kH + k] : Whh1[g * kH + (k - 64)];
        v[j] = (f16)wv;
      }
      Bw[a][q] = v;
    }
  }

  // Row map: batch row r -> M-row m = 4r. Lane (quad,c): real cell is
  // M-row 4*quad (batch row r = quad), acc element [0], h-col = 16w+c.
  float cst = 0.f;
  const int hcol = w * 16 + c;
  const int mym = 4 * quad;      // M-row this lane updates

  // x staging: 84 group-B threads, one float2 each; batch row srr -> m=4*srr
  const float* xbase = x + (size_t)row0 * kT * kIn;
  const int stid = tid - 256;
  const bool stager = (!isA) && (stid < 84);
  const int srr = stager ? stid / 21 : 0;
  const int sp = stager ? stid - srr * 21 : 0;
  const int sm = 4 * srr;

  if (stager) {  // pre-stage x(0) into slot 0
    const float2 v = *(const float2*)(xbase + (size_t)srr * kT * kIn + 2 * sp);
    f16x2 hv; hv.x = (f16)v.x; hv.y = (f16)v.y;
    *(f16x2*)&xh0[sm * kKP + 2 * sp] = hv;
  }
  __syncthreads();

  // iter i: A computes layer0(t=i), B computes layer1(t=i-1)
  const f16* arb = (isA ? xh0 : xh1) + c * kKP + quad * 8;

  for (int i = 0; i <= kT; ++i) {
    const int cur = i & 1, nxt = cur ^ 1;
    const bool act = isA ? (i < kT) : (i > 0);

    float2 xv;
    const bool havex = stager && (i + 1 < kT);
    if (havex)
      xv = *(const float2*)(xbase + (size_t)srr * kT * kIn + (size_t)(i + 1) * kIn + 2 * sp);

    if (act) {
      const f16* ar = arb + cur * kSlot;
      f32x4 acc[4];
#pragma unroll
      for (int a = 0; a < 4; ++a) acc[a] = (f32x4){bias[a], bias[a], bias[a], bias[a]};
      // q-halves: only 2 A-fragments (8 regs) live at a time
#pragma unroll
      for (int qh = 0; qh < 2; ++qh) {
        f16x8 A0 = __builtin_bit_cast(f16x8, *(const float4*)(ar + (2 * qh) * 32));
        f16x8 A1 = __builtin_bit_cast(f16x8, *(const float4*)(ar + (2 * qh + 1) * 32));
#pragma unroll
        for (int a = 0; a < 4; ++a)
          acc[a] = __builtin_amdgcn_mfma_f32_16x16x32_f16(A0, Bw[a][2 * qh], acc[a], 0, 0, 0);
#pragma unroll
        for (int a = 0; a < 4; ++a)
          acc[a] = __builtin_amdgcn_mfma_f32_16x16x32_f16(A1, Bw[a][2 * qh + 1], acc[a], 0, 0, 0);
      }
      // single real cell per lane: acc element [0] (STATIC index)
      const float gi = acc[0][0], gf = acc[1][0], gg = acc[2][0], go = acc[3][0];
      cst = sig_(gf) * cst + sig_(gi) * tnh_(gg);
      const f16 h = (f16)(sig_(go) * tnh_(cst));
      if (isA) {
        xh0[nxt * kSlot + mym * kKP + 42 + hcol] = h;  // A's next step
        xh1[nxt * kSlot + mym * kKP + hcol] = h;       // B's next iteration
      } else {
        xh1[nxt * kSlot + mym * kKP + 64 + hcol] = h;  // h1 recurrent input
      }
    }
    if (havex) {
      f16x2 hv; hv.x = (f16)xv.x; hv.y = (f16)xv.y;
      *(f16x2*)&xh0[nxt * kSlot + sm * kKP + 2 * sp] = hv;
    }
    __syncthreads();  // publish nxt-slot writes; next iter reads them as cur
  }

  // ---- FC + softmax. Final h1(T-1) is in slot 1 (kT even). ----
  if (tid < kRows * 5) {
    const int rr = tid / 5, oo = tid - rr * 5;
    const int m = 4 * rr;
    float a = bfc[oo];
#pragma unroll
    for (int j = 0; j < kH; ++j)
      a += (float)xh1[kSlot + m * kKP + 64 + j] * Wfc[oo * kH + j];
    lg[rr * 8 + oo] = a;
  }
  __syncthreads();
  if (tid < kRows) {
    const float v0 = lg[tid * 8 + 0], v1 = lg[tid * 8 + 1], v2 = lg[tid * 8 + 2],
                v3 = lg[tid * 8 + 3], v4 = lg[tid * 8 + 4];
    const float m = fmaxf(fmaxf(fmaxf(v0, v1), fmaxf(v2, v3)), v4);
    const float e0 = __expf(v0 - m), e1 = __expf(v1 - m), e2 = __expf(v2 - m),
                e3 = __expf(v3 - m), e4 = __expf(v4 - m);
    const float inv = __fdividef(1.0f, e0 + e1 + e2 + e3 + e4);
    float* o = out + (size_t)(row0 + tid) * 5;
    o[0] = e0 * inv; o[1] = e1 * inv; o[2] = e2 * inv; o[3] = e3 * inv; o[4] = e4 * inv;
  }
}

extern "C" void kernel_launch(void* const* d_in, const int* in_sizes, int n_in,
                              void* d_out, int out_size, void* d_ws, size_t ws_size,
                              hipStream_t stream) {
  (void)in_sizes; (void)n_in; (void)d_ws; (void)ws_size; (void)out_size;
  lstm_occ2_kernel<<<dim3(512), dim3(kThr), 0, stream>>>(
      (const float*)d_in[0],
      (const float*)d_in[1], (const float*)d_in[2],
      (const float*)d_in[3], (const float*)d_in[4],
      (const float*)d_in[5], (const float*)d_in[6],
      (const float*)d_in[7], (const float*)d_in[8],
      (const float*)d_in[9], (const float*)d_in[10],
      (float*)d_out);
}